// Round 6
// baseline (162.728 us; speedup 1.0000x reference)
//
#include <hip/hip_runtime.h>

#define NB_MAX   1568   // buckets: ceil(100000/64)=1563, padded
#define CAP      1024   // fixed per-bucket record capacity (mean 768, +9σ safe)
#define BT_EDGES 5120   // edges per build tile -> grid 235 <= 256 CUs (no 2-block tail)
#define BT_TPB   1024
#define EPE      5      // edges per thread in build (5120/1024)

typedef __attribute__((ext_vector_type(4))) float floatx4;
typedef __attribute__((ext_vector_type(2))) float floatx2;
typedef __attribute__((ext_vector_type(8))) short bf16x8;
typedef __attribute__((ext_vector_type(4))) unsigned uintx4;

__device__ __forceinline__ unsigned short f32_to_bf16(float f) {
  unsigned u = __float_as_uint(f);
  u = (u + 0x7fffu + ((u >> 16) & 1u)) >> 16;  // RNE
  return (unsigned short)u;
}
__device__ __forceinline__ unsigned pack2(float a, float b) {
  return (unsigned)f32_to_bf16(a) | ((unsigned)f32_to_bf16(b) << 16);
}
__device__ __forceinline__ bf16x8 zero_bf16x8() {
  bf16x8 v;
#pragma unroll
  for (int i = 0; i < 8; ++i) v[i] = 0;
  return v;
}

// ---- fp8 e4m3fn helpers (HW path on gfx950; software fallback) ------------
#if __has_builtin(__builtin_amdgcn_cvt_pk_fp8_f32)
__device__ __forceinline__ unsigned pack_fp8x4(float a, float b, float c, float d) {
  unsigned v = (unsigned)__builtin_amdgcn_cvt_pk_fp8_f32(a, b, 0, false);
  v = (unsigned)__builtin_amdgcn_cvt_pk_fp8_f32(c, d, (int)v, true);
  return v;
}
#else
__device__ __forceinline__ unsigned sw_f32_fp8(float f) {
  unsigned u = __float_as_uint(f);
  unsigned s = (u >> 24) & 0x80u;
  unsigned au = u & 0x7fffffffu;
  if (au > 0x43E00000u) au = 0x43E00000u;      // clamp to 448
  au += 0x7FFFFu + ((au >> 20) & 1u);          // RNE at bit 20
  int e = (int)(au >> 23) - 120;               // fp8 exponent
  if (e <= 0) return s;                        // flush underflow to ±0
  return s | ((unsigned)e << 3) | ((au >> 20) & 7u);
}
__device__ __forceinline__ unsigned pack_fp8x4(float a, float b, float c, float d) {
  return sw_f32_fp8(a) | (sw_f32_fp8(b) << 8) | (sw_f32_fp8(c) << 16) |
         (sw_f32_fp8(d) << 24);
}
#endif

#if __has_builtin(__builtin_amdgcn_cvt_pk_f32_fp8)
__device__ __forceinline__ void dec4(float* acc, unsigned w32, float wt) {
  floatx2 f0 = __builtin_amdgcn_cvt_pk_f32_fp8((int)w32, false);
  floatx2 f1 = __builtin_amdgcn_cvt_pk_f32_fp8((int)w32, true);
  acc[0] += wt * f0.x; acc[1] += wt * f0.y;
  acc[2] += wt * f1.x; acc[3] += wt * f1.y;
}
#else
__device__ __forceinline__ float sw_fp8_f32(unsigned b) {
  unsigned s = (b & 0x80u) << 24;
  unsigned e = (b >> 3) & 0xFu;
  unsigned m = b & 7u;
  float fn = __uint_as_float(s | ((e + 120u) << 23) | (m << 20));
  float fd = (float)(int)m * 0.001953125f;      // 2^-9
  fd = (b & 0x80u) ? -fd : fd;
  return e ? fn : fd;
}
__device__ __forceinline__ void dec4(float* acc, unsigned w32, float wt) {
  acc[0] += wt * sw_fp8_f32(w32 & 0xFF);
  acc[1] += wt * sw_fp8_f32((w32 >> 8) & 0xFF);
  acc[2] += wt * sw_fp8_f32((w32 >> 16) & 0xFF);
  acc[3] += wt * sw_fp8_f32(w32 >> 24);
}
#endif

// ---------------------------------------------------------------------------
// Single-pass build (v8): v7 + featq written as TWO dim-planes:
//   plane0 = all nodes' dims 0..31 (N*32 B = 3.2 MB)
//   plane1 = all nodes' dims 32..63 (3.2 MB, at featq + N*32)
// so the gather can do a two-phase sweep whose random working set fits the
// 4 MB per-XCD L2.  Chunk c (8 floats) of node n = c>>3, half h = (c>>2)&1,
// subchunk j = c&3 -> plane h, uint2 index n*4 + j.  Per-wave writes stay
// contiguous per plane (8 nodes x 32 B).
// Record (32-bit): src(0..16) | dL(17..22) | w9(23..31).
// LDS: stage 20K + stageB 10K + A/B 12.5K = 43.3 KB (1 block/CU).
// ---------------------------------------------------------------------------
__global__ __launch_bounds__(BT_TPB) void k_build(
    const float* __restrict__ feat, const int* __restrict__ src,
    const int* __restrict__ dst, const float* __restrict__ ew,
    const float* __restrict__ em, const float* __restrict__ Ws,
    const float* __restrict__ Wn, int* __restrict__ gCursor,
    unsigned* __restrict__ recs, unsigned short* __restrict__ featb,
    unsigned char* __restrict__ featq, unsigned short* __restrict__ Wb,
    int E, int nChunks, int nB) {
  __shared__ unsigned stage[BT_EDGES];         // bucket-sorted rec32 (20 KB)
  __shared__ unsigned short stageB[BT_EDGES];  // bucket id per slot   (10 KB)
  __shared__ int A[NB_MAX];                    // loff -> writebase-loff
  __shared__ int B[NB_MAX];                    // cnt -> cursor -> ends
  __shared__ int waveSums[16];

  const int t = threadIdx.x;
  const int lane = t & 63;
  const int wvid = t >> 6;
  const int e0 = blockIdx.x * BT_EDGES;
  const int eEnd = min(e0 + BT_EDGES, E);
  const int nLocal = eEnd - e0;

  for (int i = t; i < NB_MAX; i += BT_TPB) B[i] = 0;
  __syncthreads();

  // pass 1: histogram + full record precompute (loads overlap scan below)
  int dreg[EPE];        // dst (or -1)
  unsigned rreg[EPE];   // precomputed rec32
#pragma unroll
  for (int k = 0; k < EPE; ++k) {
    int i = e0 + k * BT_TPB + t;
    dreg[k] = -1;
    if (i < eEnd) {
      int d = __builtin_nontemporal_load(&dst[i]);
      dreg[k] = d;
      atomicAdd(&B[d >> 6], 1);
      float w = __builtin_nontemporal_load(&ew[i]) *
                __builtin_nontemporal_load(&em[i]);
      int wq = (int)(w * 511.0f + 0.5f);
      if (wq > 511) wq = 511;
      rreg[k] = (unsigned)__builtin_nontemporal_load(&src[i]) |
                ((unsigned)(d & 63) << 17) | ((unsigned)wq << 23);
    }
  }
  __syncthreads();

  // exclusive scan of B -> A via wave shuffles (EPT=2, 1024*2=2048 >= NB_MAX)
  {
    const int EPT = 2;
    int b0 = t * EPT;
    int v[EPT];
    int sum = 0;
#pragma unroll
    for (int j = 0; j < EPT; ++j) {
      v[j] = (b0 + j < nB) ? B[b0 + j] : 0;
      sum += v[j];
    }
    int x = sum;
#pragma unroll
    for (int d = 1; d < 64; d <<= 1) {
      int y = __shfl_up(x, d, 64);
      if (lane >= d) x += y;
    }
    if (lane == 63) waveSums[wvid] = x;
    __syncthreads();
    int wprefix = 0;
    for (int i = 0; i < wvid; ++i) wprefix += waveSums[i];
    int run = wprefix + x - sum;
#pragma unroll
    for (int j = 0; j < EPT; ++j) {
      if (b0 + j < nB) A[b0 + j] = run;
      run += v[j];
    }
  }
  __syncthreads();

  // reserve global ranges; B becomes staging cursor, A becomes write delta
  for (int i = t; i < nB; i += BT_TPB) {
    int c = B[i];
    int l = A[i];
    int g = c ? atomicAdd(&gCursor[i], c) : 0;
    A[i] = i * CAP + g - l;
    B[i] = l;
  }
  __syncthreads();

  // pass 2: stage rec32 + bucket id, bucket-sorted (pure LDS now)
#pragma unroll
  for (int k = 0; k < EPE; ++k) {
    if (dreg[k] >= 0) {
      int bkt = dreg[k] >> 6;
      int r = atomicAdd(&B[bkt], 1);
      stage[r] = rreg[k];
      stageB[r] = (unsigned short)bkt;
    }
  }
  __syncthreads();

  // pass 3: coalesced write-out; bucket id read directly (depth-2 LDS chain)
  for (int i = t; i < nLocal; i += BT_TPB) {
    int bkt = stageB[i];
    int pos = A[bkt] + i;
    if (pos < (bkt + 1) * CAP)  // capacity guard (never fires statistically)
      recs[pos] = stage[i];
  }

  // feat -> bf16 AND fp8 dim-planes (one read, two writes; grid-stride)
  const size_t PL = (size_t)nChunks * 4;  // N*32 bytes per plane
  for (int c = blockIdx.x * BT_TPB + t; c < nChunks; c += gridDim.x * BT_TPB) {
    const floatx4* fp = reinterpret_cast<const floatx4*>(feat) + (size_t)c * 2;
    floatx4 a = __builtin_nontemporal_load(fp);
    floatx4 b = __builtin_nontemporal_load(fp + 1);
    uintx4 o;
    o.x = pack2(a.x, a.y);
    o.y = pack2(a.z, a.w);
    o.z = pack2(b.x, b.y);
    o.w = pack2(b.z, b.w);
    __builtin_nontemporal_store(o, reinterpret_cast<uintx4*>(featb) + c);
    uint2 q8;
    q8.x = pack_fp8x4(a.x, a.y, a.z, a.w);
    q8.y = pack_fp8x4(b.x, b.y, b.z, b.w);
    int n = c >> 3, h = (c >> 2) & 1, j = c & 3;
    reinterpret_cast<uint2*>(featq + (size_t)h * PL)[(size_t)n * 4 + j] = q8;
  }

  // W -> bf16 j-major block (block 0 only)
  if (blockIdx.x == 0) {
    for (int i = t; i < 1024; i += BT_TPB) {
      int j = i >> 4, c4 = i & 15;
      float4 w4 = reinterpret_cast<const float4*>(Ws)[i];
      float4 n4 = reinterpret_cast<const float4*>(Wn)[i];
      *reinterpret_cast<uint2*>(&Wb[j * 128 + c4 * 4]) =
          make_uint2(pack2(w4.x, w4.y), pack2(w4.z, w4.w));
      *reinterpret_cast<uint2*>(&Wb[j * 128 + 64 + c4 * 4]) =
          make_uint2(pack2(n4.x, n4.y), pack2(n4.z, n4.w));
    }
  }
}

// ---------------------------------------------------------------------------
// Fused gather + dual-linear (r19): r18 structure + TWO-PHASE dim-plane
// gather.  Phase A walks the edge list reading only plane0 (3.2 MB random
// working set -> fits 4 MB per-XCD L2); phase B re-walks reading plane1.
// All 1563 blocks start together (co-resident since r17) and block edge
// counts are tight (768 +- ~30), so phase drift pollution is small; the
// streaming readers (recs/featb/out) are already non-temporal so they
// don't evict the resident plane.  Same total bytes; random misses now
// mostly L2-latency (~200cy) instead of L3/HBM (~450-900cy).
// LDS 18.2 KB; __launch_bounds__(256,8) -> 8 blocks/CU, 32 waves/CU.
// ---------------------------------------------------------------------------
__global__ __launch_bounds__(256, 8) void sage_gather_gemm(
    const unsigned short* __restrict__ featb,
    const unsigned char* __restrict__ featq,
    const unsigned short* __restrict__ Wb, const int* __restrict__ gCursor,
    const unsigned* __restrict__ recs, const float* __restrict__ bs,
    const float* __restrict__ bn, float* __restrict__ out, int N) {
  __shared__ unsigned short An[64][72];  // h_neigh bf16; stride 72
  __shared__ unsigned rawL[CAP];         // 4 KB
  __shared__ unsigned srtL[CAP];         // 4 KB
  __shared__ int cntS[64], offS[64], curS[64];

  const int t = threadIdx.x;
  const int b = blockIdx.x;
  const int n0 = b * 64;
  const int base = b * CAP;
  const int cb = min(gCursor[b], CAP);

  if (t < 64) cntS[t] = 0;
  __syncthreads();

  // merged: coalesced record load + LDS stash + histogram in one sweep
  for (int i = t; i < cb; i += 256) {
    unsigned r = __builtin_nontemporal_load(&recs[base + i]);
    rawL[i] = r;
    atomicAdd(&cntS[(r >> 17) & 63], 1);
  }
  __syncthreads();

  // exclusive scan of 64 counters: wave-0 shuffle scan
  if (t < 64) {
    int c = cntS[t];
    int x = c;
#pragma unroll
    for (int d = 1; d < 64; d <<= 1) {
      int y = __shfl_up(x, d, 64);
      if (t >= d) x += y;
    }
    offS[t] = x - c;
    curS[t] = x - c;
  }
  __syncthreads();

  // permute into node-sorted order (LDS -> LDS)
  for (int i = t; i < cb; i += 256) {
    unsigned r = rawL[i];
    int p = atomicAdd(&curS[(r >> 17) & 63], 1);
    srtL[p] = r;
  }
  __syncthreads();

  // MFMA-phase lane mapping (also used for the hoisted prefetch below)
  const int wv = t >> 6;        // node tile (16 nodes)
  const int ln = t & 63;
  const int col = ln & 15;
  const int quad = ln >> 4;
  const int gn = n0 + wv * 16 + col;
  bf16x8 af0 = zero_bf16x8(), af1 = zero_bf16x8();

  // per-node gather: 4 lanes/node; two phases, one dim-plane each
  {
    const int nl = t >> 2;        // local node 0..63
    const int q  = t & 3;         // 8-dim chunk within plane
    const int deg = cntS[nl], off = offS[nl];
    float acc[16];
#pragma unroll
    for (int i = 0; i < 16; ++i) acc[i] = 0.f;
    const uint2* fq0 = reinterpret_cast<const uint2*>(featq);  // dims 0..31
    const uint2* fq1 =
        reinterpret_cast<const uint2*>(featq + (size_t)N * 32);  // dims 32..63

    // 2-deep single-edge pipeline per phase; u regs zero-init so a w=0
    // decode can never be 0*NaN (encoder clamps to 448, no e4m3fn NaN).
#define GPHASE(FQ, A0, A1)                                   \
    {                                                        \
      uint2 uC = {0, 0}, uN = {0, 0};                        \
      float wC = 0.f, wN = 0.f;                              \
      if (deg > 0) {                                         \
        unsigned r0 = srtL[off];                             \
        uC = FQ[(size_t)(r0 & 0x1FFFF) * 4 + q];             \
        wC = (float)(r0 >> 23) * (1.0f / 511.0f);            \
      }                                                      \
      if (deg > 1) {                                         \
        unsigned r1 = srtL[off + 1];                         \
        uN = FQ[(size_t)(r1 & 0x1FFFF) * 4 + q];             \
        wN = (float)(r1 >> 23) * (1.0f / 511.0f);            \
      }                                                      \
      for (int m = 0; m < deg; ++m) {                        \
        uint2 u = uC;                                        \
        float w = wC;                                        \
        uC = uN; wC = wN;                                    \
        if (m + 2 < deg) {                                   \
          unsigned rn = srtL[off + m + 2];                   \
          uN = FQ[(size_t)(rn & 0x1FFFF) * 4 + q];           \
          wN = (float)(rn >> 23) * (1.0f / 511.0f);          \
        }                                                    \
        dec4(acc + (A0), u.x, w);                            \
        dec4(acc + (A1), u.y, w);                            \
      }                                                      \
    }
    GPHASE(fq0, 0, 4)   // dims q*8..q*8+7        -> acc[0..7]
    GPHASE(fq1, 8, 12)  // dims 32+q*8..32+q*8+7  -> acc[8..15]
#undef GPHASE

    float inv = 1.0f / fmaxf((float)deg, 1.0f);
#pragma unroll
    for (int i = 0; i < 16; ++i) acc[i] *= inv;
    uint4 o0, o1;
    o0.x = pack2(acc[0], acc[1]);
    o0.y = pack2(acc[2], acc[3]);
    o0.z = pack2(acc[4], acc[5]);
    o0.w = pack2(acc[6], acc[7]);
    o1.x = pack2(acc[8], acc[9]);
    o1.y = pack2(acc[10], acc[11]);
    o1.z = pack2(acc[12], acc[13]);
    o1.w = pack2(acc[14], acc[15]);
    // phase A covered dims q*8..q*8+7, phase B dims 32+q*8..32+q*8+7
    *reinterpret_cast<uint4*>(&An[nl][q * 8]) = o0;
    *reinterpret_cast<uint4*>(&An[nl][32 + q * 8]) = o1;
  }

  // hoisted: issue self-term rows + biases NOW; latency hides under the
  // barrier wait for straggler waves still in their gather loops.
  if (gn < N) {
    af0 = __builtin_nontemporal_load(
        reinterpret_cast<const bf16x8*>(featb + (size_t)gn * 64 + quad * 8));
    af1 = __builtin_nontemporal_load(
        reinterpret_cast<const bf16x8*>(featb + (size_t)gn * 64 + 32 + quad * 8));
  }
  floatx4 acc4[4];
#pragma unroll
  for (int jt = 0; jt < 4; ++jt) {
    float bb = bs[jt * 16 + col] + bn[jt * 16 + col];
    acc4[jt] = (floatx4){bb, bb, bb, bb};
  }
  __syncthreads();

  // MFMA phase: 4 waves = 4 node-tiles; each wave does all 4 j-tiles
#pragma unroll
  for (int kk = 0; kk < 4; ++kk) {
    bf16x8 af;
    if (kk == 0)      af = af0;
    else if (kk == 1) af = af1;
    else
      af = *reinterpret_cast<const bf16x8*>(
          &An[wv * 16 + col][(kk - 2) * 32 + quad * 8]);
#pragma unroll
    for (int jt = 0; jt < 4; ++jt) {
      bf16x8 bf = *reinterpret_cast<const bf16x8*>(
          Wb + (jt * 16 + col) * 128 + kk * 32 + quad * 8);
      acc4[jt] = __builtin_amdgcn_mfma_f32_16x16x32_bf16(af, bf, acc4[jt], 0, 0, 0);
    }
  }

#pragma unroll
  for (int jt = 0; jt < 4; ++jt) {
#pragma unroll
    for (int r = 0; r < 4; ++r) {
      int m = quad * 4 + r;
      int g2 = n0 + wv * 16 + m;
      if (g2 < N)
        __builtin_nontemporal_store(acc4[jt][r],
                                    &out[(size_t)g2 * 64 + jt * 16 + col]);
    }
  }
}

extern "C" void kernel_launch(void* const* d_in, const int* in_sizes, int n_in,
                              void* d_out, int out_size, void* d_ws, size_t ws_size,
                              hipStream_t stream) {
  const float* feat = (const float*)d_in[0];
  const int*   src  = (const int*)d_in[1];
  const int*   dst  = (const int*)d_in[2];
  const float* ew   = (const float*)d_in[3];
  const float* em   = (const float*)d_in[4];
  const float* Ws   = (const float*)d_in[5];
  const float* bs   = (const float*)d_in[6];
  const float* Wn   = (const float*)d_in[7];
  const float* bn   = (const float*)d_in[8];
  float* out = (float*)d_out;

  const int N = in_sizes[0] / 64;  // 100000
  const int E = in_sizes[1];       // 1200000
  const int nB = (N + 63) / 64;    // 1563

  // Workspace: featb 12.8MB | featq 6.4MB (2 planes) | Wb 16KB | recs 6.4MB
  unsigned short* featb = (unsigned short*)d_ws;
  unsigned char*  featq = (unsigned char*)(featb + (size_t)N * 64);
  unsigned short* Wb    = (unsigned short*)(featq + (size_t)N * 64);
  unsigned* recs   = (unsigned*)(Wb + 64 * 128);
  int*      gCursor = (int*)(recs + (size_t)NB_MAX * CAP);

  hipMemsetAsync(gCursor, 0, NB_MAX * sizeof(int), stream);

  int nChunks = N * 8;  // 8-float conversion chunks
  int gB = (E + BT_EDGES - 1) / BT_EDGES;  // 235 blocks (one per CU)

  k_build<<<gB, BT_TPB, 0, stream>>>(feat, src, dst, ew, em, Ws, Wn,
                                     gCursor, recs, featb, featq, Wb,
                                     E, nChunks, nB);
  sage_gather_gemm<<<nB, 256, 0, stream>>>(featb, featq, Wb, gCursor, recs,
                                           bs, bn, out, N);
}

// Round 7
// 156.875 us; speedup vs baseline: 1.0373x; 1.0373x over previous
//
#include <hip/hip_runtime.h>

#define NB_MAX   1568   // buckets: ceil(100000/64)=1563, padded
#define CAP      1024   // fixed per-bucket record capacity (mean 768, +9σ safe)
#define BT_EDGES 5120   // edges per build tile -> grid 235 <= 256 CUs (no 2-block tail)
#define BT_TPB   1024
#define EPE      5      // edges per thread in build (5120/1024)

typedef __attribute__((ext_vector_type(4))) float floatx4;
typedef __attribute__((ext_vector_type(2))) float floatx2;
typedef __attribute__((ext_vector_type(8))) short bf16x8;
typedef __attribute__((ext_vector_type(4))) unsigned uintx4;

__device__ __forceinline__ unsigned short f32_to_bf16(float f) {
  unsigned u = __float_as_uint(f);
  u = (u + 0x7fffu + ((u >> 16) & 1u)) >> 16;  // RNE
  return (unsigned short)u;
}
__device__ __forceinline__ unsigned pack2(float a, float b) {
  return (unsigned)f32_to_bf16(a) | ((unsigned)f32_to_bf16(b) << 16);
}
__device__ __forceinline__ bf16x8 zero_bf16x8() {
  bf16x8 v;
#pragma unroll
  for (int i = 0; i < 8; ++i) v[i] = 0;
  return v;
}

// ---- fp8 e4m3fn helpers (HW path on gfx950; software fallback) ------------
#if __has_builtin(__builtin_amdgcn_cvt_pk_fp8_f32)
__device__ __forceinline__ unsigned pack_fp8x4(float a, float b, float c, float d) {
  unsigned v = (unsigned)__builtin_amdgcn_cvt_pk_fp8_f32(a, b, 0, false);
  v = (unsigned)__builtin_amdgcn_cvt_pk_fp8_f32(c, d, (int)v, true);
  return v;
}
#else
__device__ __forceinline__ unsigned sw_f32_fp8(float f) {
  unsigned u = __float_as_uint(f);
  unsigned s = (u >> 24) & 0x80u;
  unsigned au = u & 0x7fffffffu;
  if (au > 0x43E00000u) au = 0x43E00000u;      // clamp to 448
  au += 0x7FFFFu + ((au >> 20) & 1u);          // RNE at bit 20
  int e = (int)(au >> 23) - 120;               // fp8 exponent
  if (e <= 0) return s;                        // flush underflow to ±0
  return s | ((unsigned)e << 3) | ((au >> 20) & 7u);
}
__device__ __forceinline__ unsigned pack_fp8x4(float a, float b, float c, float d) {
  return sw_f32_fp8(a) | (sw_f32_fp8(b) << 8) | (sw_f32_fp8(c) << 16) |
         (sw_f32_fp8(d) << 24);
}
#endif

#if __has_builtin(__builtin_amdgcn_cvt_pk_f32_fp8)
__device__ __forceinline__ void dec4(float* acc, unsigned w32, float wt) {
  floatx2 f0 = __builtin_amdgcn_cvt_pk_f32_fp8((int)w32, false);
  floatx2 f1 = __builtin_amdgcn_cvt_pk_f32_fp8((int)w32, true);
  acc[0] += wt * f0.x; acc[1] += wt * f0.y;
  acc[2] += wt * f1.x; acc[3] += wt * f1.y;
}
#else
__device__ __forceinline__ float sw_fp8_f32(unsigned b) {
  unsigned s = (b & 0x80u) << 24;
  unsigned e = (b >> 3) & 0xFu;
  unsigned m = b & 7u;
  float fn = __uint_as_float(s | ((e + 120u) << 23) | (m << 20));
  float fd = (float)(int)m * 0.001953125f;      // 2^-9
  fd = (b & 0x80u) ? -fd : fd;
  return e ? fn : fd;
}
__device__ __forceinline__ void dec4(float* acc, unsigned w32, float wt) {
  acc[0] += wt * sw_fp8_f32(w32 & 0xFF);
  acc[1] += wt * sw_fp8_f32((w32 >> 8) & 0xFF);
  acc[2] += wt * sw_fp8_f32((w32 >> 16) & 0xFF);
  acc[3] += wt * sw_fp8_f32(w32 >> 24);
}
#endif

// ---------------------------------------------------------------------------
// Single-pass build (v9 = v7): fused edge-stream loads in pass 1; featq back
// to SINGLE row-major plane (64B rows -> minimal 1 transaction/edge in
// gather; the r19 dim-plane split doubled transactions and regressed).
// Record (32-bit): src(0..16) | dL(17..22) | w9(23..31).
// LDS: stage 20K + stageB 10K + A/B 12.5K = 43.3 KB (1 block/CU).
// ---------------------------------------------------------------------------
__global__ __launch_bounds__(BT_TPB) void k_build(
    const float* __restrict__ feat, const int* __restrict__ src,
    const int* __restrict__ dst, const float* __restrict__ ew,
    const float* __restrict__ em, const float* __restrict__ Ws,
    const float* __restrict__ Wn, int* __restrict__ gCursor,
    unsigned* __restrict__ recs, unsigned short* __restrict__ featb,
    unsigned char* __restrict__ featq, unsigned short* __restrict__ Wb,
    int E, int nChunks, int nB) {
  __shared__ unsigned stage[BT_EDGES];         // bucket-sorted rec32 (20 KB)
  __shared__ unsigned short stageB[BT_EDGES];  // bucket id per slot   (10 KB)
  __shared__ int A[NB_MAX];                    // loff -> writebase-loff
  __shared__ int B[NB_MAX];                    // cnt -> cursor -> ends
  __shared__ int waveSums[16];

  const int t = threadIdx.x;
  const int lane = t & 63;
  const int wvid = t >> 6;
  const int e0 = blockIdx.x * BT_EDGES;
  const int eEnd = min(e0 + BT_EDGES, E);
  const int nLocal = eEnd - e0;

  for (int i = t; i < NB_MAX; i += BT_TPB) B[i] = 0;
  __syncthreads();

  // pass 1: histogram + full record precompute (loads overlap scan below)
  int dreg[EPE];        // dst (or -1)
  unsigned rreg[EPE];   // precomputed rec32
#pragma unroll
  for (int k = 0; k < EPE; ++k) {
    int i = e0 + k * BT_TPB + t;
    dreg[k] = -1;
    if (i < eEnd) {
      int d = __builtin_nontemporal_load(&dst[i]);
      dreg[k] = d;
      atomicAdd(&B[d >> 6], 1);
      float w = __builtin_nontemporal_load(&ew[i]) *
                __builtin_nontemporal_load(&em[i]);
      int wq = (int)(w * 511.0f + 0.5f);
      if (wq > 511) wq = 511;
      rreg[k] = (unsigned)__builtin_nontemporal_load(&src[i]) |
                ((unsigned)(d & 63) << 17) | ((unsigned)wq << 23);
    }
  }
  __syncthreads();

  // exclusive scan of B -> A via wave shuffles (EPT=2, 1024*2=2048 >= NB_MAX)
  {
    const int EPT = 2;
    int b0 = t * EPT;
    int v[EPT];
    int sum = 0;
#pragma unroll
    for (int j = 0; j < EPT; ++j) {
      v[j] = (b0 + j < nB) ? B[b0 + j] : 0;
      sum += v[j];
    }
    int x = sum;
#pragma unroll
    for (int d = 1; d < 64; d <<= 1) {
      int y = __shfl_up(x, d, 64);
      if (lane >= d) x += y;
    }
    if (lane == 63) waveSums[wvid] = x;
    __syncthreads();
    int wprefix = 0;
    for (int i = 0; i < wvid; ++i) wprefix += waveSums[i];
    int run = wprefix + x - sum;
#pragma unroll
    for (int j = 0; j < EPT; ++j) {
      if (b0 + j < nB) A[b0 + j] = run;
      run += v[j];
    }
  }
  __syncthreads();

  // reserve global ranges; B becomes staging cursor, A becomes write delta
  for (int i = t; i < nB; i += BT_TPB) {
    int c = B[i];
    int l = A[i];
    int g = c ? atomicAdd(&gCursor[i], c) : 0;
    A[i] = i * CAP + g - l;
    B[i] = l;
  }
  __syncthreads();

  // pass 2: stage rec32 + bucket id, bucket-sorted (pure LDS now)
#pragma unroll
  for (int k = 0; k < EPE; ++k) {
    if (dreg[k] >= 0) {
      int bkt = dreg[k] >> 6;
      int r = atomicAdd(&B[bkt], 1);
      stage[r] = rreg[k];
      stageB[r] = (unsigned short)bkt;
    }
  }
  __syncthreads();

  // pass 3: coalesced write-out; bucket id read directly (depth-2 LDS chain)
  for (int i = t; i < nLocal; i += BT_TPB) {
    int bkt = stageB[i];
    int pos = A[bkt] + i;
    if (pos < (bkt + 1) * CAP)  // capacity guard (never fires statistically)
      recs[pos] = stage[i];
  }

  // feat -> bf16 AND fp8 (one read, two writes; grid-stride tail work)
  for (int c = blockIdx.x * BT_TPB + t; c < nChunks; c += gridDim.x * BT_TPB) {
    const floatx4* fp = reinterpret_cast<const floatx4*>(feat) + (size_t)c * 2;
    floatx4 a = __builtin_nontemporal_load(fp);
    floatx4 b = __builtin_nontemporal_load(fp + 1);
    uintx4 o;
    o.x = pack2(a.x, a.y);
    o.y = pack2(a.z, a.w);
    o.z = pack2(b.x, b.y);
    o.w = pack2(b.z, b.w);
    __builtin_nontemporal_store(o, reinterpret_cast<uintx4*>(featb) + c);
    uint2 q8;
    q8.x = pack_fp8x4(a.x, a.y, a.z, a.w);
    q8.y = pack_fp8x4(b.x, b.y, b.z, b.w);
    reinterpret_cast<uint2*>(featq)[c] = q8;  // cached: gather re-reads this
  }

  // W -> bf16 j-major block (block 0 only)
  if (blockIdx.x == 0) {
    for (int i = t; i < 1024; i += BT_TPB) {
      int j = i >> 4, c4 = i & 15;
      float4 w4 = reinterpret_cast<const float4*>(Ws)[i];
      float4 n4 = reinterpret_cast<const float4*>(Wn)[i];
      *reinterpret_cast<uint2*>(&Wb[j * 128 + c4 * 4]) =
          make_uint2(pack2(w4.x, w4.y), pack2(w4.z, w4.w));
      *reinterpret_cast<uint2*>(&Wb[j * 128 + 64 + c4 * 4]) =
          make_uint2(pack2(n4.x, n4.y), pack2(n4.z, n4.w));
    }
  }
}

// ---------------------------------------------------------------------------
// Fused gather + dual-linear (r20): r18 structure + SRC-HALF two-phase walk.
// LDS sort key widened to (localNode, src>=N/2) -> 128 buckets.  Phase A
// walks each node's src-lo edges (random working set = featq rows [0,N/2)
// = 3.2 MB < 4 MB/XCD L2); phase B walks src-hi edges (other 3.2 MB).
// vs r19 (which halved per-phase working set but DOUBLED transactions and
// regressed; its FETCH drop 52->34 MB proved residency engages): each edge
// is processed exactly ONCE with the minimal 1x64B-line access -- same
// transaction count as r18, L2-sized working set per phase.
// All 1563 blocks co-resident with tight work (768+-30 edges, A/B 384+-14)
// -> small cross-block phase drift.
// LDS ~19 KB; __launch_bounds__(256,8) -> 8 blocks/CU, 32 waves/CU.
// ---------------------------------------------------------------------------
__global__ __launch_bounds__(256, 8) void sage_gather_gemm(
    const unsigned short* __restrict__ featb,
    const unsigned char* __restrict__ featq,
    const unsigned short* __restrict__ Wb, const int* __restrict__ gCursor,
    const unsigned* __restrict__ recs, const float* __restrict__ bs,
    const float* __restrict__ bn, float* __restrict__ out, int N) {
  __shared__ unsigned short An[64][72];  // h_neigh bf16; stride 72
  __shared__ unsigned rawL[CAP];         // 4 KB
  __shared__ unsigned srtL[CAP];         // 4 KB
  __shared__ int cntS[128], offS[128], curS[128];  // (node, src-half) buckets

  const int t = threadIdx.x;
  const int b = blockIdx.x;
  const int n0 = b * 64;
  const int base = b * CAP;
  const int cb = min(gCursor[b], CAP);
  const unsigned half = (unsigned)(N >> 1);

  if (t < 128) cntS[t] = 0;
  __syncthreads();

  // merged: coalesced record load + LDS stash + histogram in one sweep
  for (int i = t; i < cb; i += 256) {
    unsigned r = __builtin_nontemporal_load(&recs[base + i]);
    rawL[i] = r;
    int key = (int)(((r >> 17) & 63) << 1) + (int)((r & 0x1FFFFu) >= half);
    atomicAdd(&cntS[key], 1);
  }
  __syncthreads();

  // exclusive scan of 128 counters: wave-0 shuffle scan, 2 entries/lane
  if (t < 64) {
    int v0 = cntS[2 * t], v1 = cntS[2 * t + 1];
    int sum = v0 + v1;
    int x = sum;
#pragma unroll
    for (int d = 1; d < 64; d <<= 1) {
      int y = __shfl_up(x, d, 64);
      if (t >= d) x += y;
    }
    int e0 = x - sum;
    offS[2 * t] = e0;
    offS[2 * t + 1] = e0 + v0;
    curS[2 * t] = e0;
    curS[2 * t + 1] = e0 + v0;
  }
  __syncthreads();

  // permute into (node, src-half)-sorted order (LDS -> LDS)
  for (int i = t; i < cb; i += 256) {
    unsigned r = rawL[i];
    int key = (int)(((r >> 17) & 63) << 1) + (int)((r & 0x1FFFFu) >= half);
    int p = atomicAdd(&curS[key], 1);
    srtL[p] = r;
  }
  __syncthreads();

  // MFMA-phase lane mapping (also used for the hoisted prefetch below)
  const int wv = t >> 6;        // node tile (16 nodes)
  const int ln = t & 63;
  const int col = ln & 15;
  const int quad = ln >> 4;
  const int gn = n0 + wv * 16 + col;
  bf16x8 af0 = zero_bf16x8(), af1 = zero_bf16x8();

  // per-node gather: 4 lanes/node (dim-quads); src-lo walk then src-hi walk
  {
    const int nl = t >> 2;        // local node 0..63
    const int q  = t & 3;         // 16-dim chunk
    const int degA = cntS[2 * nl], offA = offS[2 * nl];
    const int degB = cntS[2 * nl + 1], offB = offS[2 * nl + 1];
    const int deg = degA + degB;
    float acc[16];
#pragma unroll
    for (int i = 0; i < 16; ++i) acc[i] = 0.f;
    const uint4* fq = reinterpret_cast<const uint4*>(featq);  // row = 4 uint4

    // 2-deep single-edge pipeline per src-half walk; u regs zero-init so a
    // w=0 decode can never be 0*NaN (encoder clamps to 448, no e4m3fn NaN).
#define GWALK(OFF, DEG)                                      \
    {                                                        \
      uint4 uC = {0, 0, 0, 0}, uN = {0, 0, 0, 0};            \
      float wC = 0.f, wN = 0.f;                              \
      if ((DEG) > 0) {                                       \
        unsigned r0 = srtL[(OFF)];                           \
        uC = fq[(size_t)(r0 & 0x1FFFF) * 4 + q];             \
        wC = (float)(r0 >> 23) * (1.0f / 511.0f);            \
      }                                                      \
      if ((DEG) > 1) {                                       \
        unsigned r1 = srtL[(OFF) + 1];                       \
        uN = fq[(size_t)(r1 & 0x1FFFF) * 4 + q];             \
        wN = (float)(r1 >> 23) * (1.0f / 511.0f);            \
      }                                                      \
      for (int m = 0; m < (DEG); ++m) {                      \
        uint4 u = uC;                                        \
        float w = wC;                                        \
        uC = uN; wC = wN;                                    \
        if (m + 2 < (DEG)) {                                 \
          unsigned rn = srtL[(OFF) + m + 2];                 \
          uN = fq[(size_t)(rn & 0x1FFFF) * 4 + q];           \
          wN = (float)(rn >> 23) * (1.0f / 511.0f);          \
        }                                                    \
        dec4(acc + 0, u.x, w);                               \
        dec4(acc + 4, u.y, w);                               \
        dec4(acc + 8, u.z, w);                               \
        dec4(acc + 12, u.w, w);                              \
      }                                                      \
    }
    GWALK(offA, degA)   // src in [0, N/2): 3.2 MB working set
    GWALK(offB, degB)   // src in [N/2, N): other 3.2 MB
#undef GWALK

    float inv = 1.0f / fmaxf((float)deg, 1.0f);
#pragma unroll
    for (int i = 0; i < 16; ++i) acc[i] *= inv;
    uint4 o0, o1;
    o0.x = pack2(acc[0], acc[1]);
    o0.y = pack2(acc[2], acc[3]);
    o0.z = pack2(acc[4], acc[5]);
    o0.w = pack2(acc[6], acc[7]);
    o1.x = pack2(acc[8], acc[9]);
    o1.y = pack2(acc[10], acc[11]);
    o1.z = pack2(acc[12], acc[13]);
    o1.w = pack2(acc[14], acc[15]);
    *reinterpret_cast<uint4*>(&An[nl][q * 16]) = o0;
    *reinterpret_cast<uint4*>(&An[nl][q * 16 + 8]) = o1;
  }

  // hoisted: issue self-term rows + biases NOW; latency hides under the
  // barrier wait for straggler waves still in their gather loops.
  if (gn < N) {
    af0 = __builtin_nontemporal_load(
        reinterpret_cast<const bf16x8*>(featb + (size_t)gn * 64 + quad * 8));
    af1 = __builtin_nontemporal_load(
        reinterpret_cast<const bf16x8*>(featb + (size_t)gn * 64 + 32 + quad * 8));
  }
  floatx4 acc4[4];
#pragma unroll
  for (int jt = 0; jt < 4; ++jt) {
    float bb = bs[jt * 16 + col] + bn[jt * 16 + col];
    acc4[jt] = (floatx4){bb, bb, bb, bb};
  }
  __syncthreads();

  // MFMA phase: 4 waves = 4 node-tiles; each wave does all 4 j-tiles
#pragma unroll
  for (int kk = 0; kk < 4; ++kk) {
    bf16x8 af;
    if (kk == 0)      af = af0;
    else if (kk == 1) af = af1;
    else
      af = *reinterpret_cast<const bf16x8*>(
          &An[wv * 16 + col][(kk - 2) * 32 + quad * 8]);
#pragma unroll
    for (int jt = 0; jt < 4; ++jt) {
      bf16x8 bf = *reinterpret_cast<const bf16x8*>(
          Wb + (jt * 16 + col) * 128 + kk * 32 + quad * 8);
      acc4[jt] = __builtin_amdgcn_mfma_f32_16x16x32_bf16(af, bf, acc4[jt], 0, 0, 0);
    }
  }

#pragma unroll
  for (int jt = 0; jt < 4; ++jt) {
#pragma unroll
    for (int r = 0; r < 4; ++r) {
      int m = quad * 4 + r;
      int g2 = n0 + wv * 16 + m;
      if (g2 < N)
        __builtin_nontemporal_store(acc4[jt][r],
                                    &out[(size_t)g2 * 64 + jt * 16 + col]);
    }
  }
}

extern "C" void kernel_launch(void* const* d_in, const int* in_sizes, int n_in,
                              void* d_out, int out_size, void* d_ws, size_t ws_size,
                              hipStream_t stream) {
  const float* feat = (const float*)d_in[0];
  const int*   src  = (const int*)d_in[1];
  const int*   dst  = (const int*)d_in[2];
  const float* ew   = (const float*)d_in[3];
  const float* em   = (const float*)d_in[4];
  const float* Ws   = (const float*)d_in[5];
  const float* bs   = (const float*)d_in[6];
  const float* Wn   = (const float*)d_in[7];
  const float* bn   = (const float*)d_in[8];
  float* out = (float*)d_out;

  const int N = in_sizes[0] / 64;  // 100000
  const int E = in_sizes[1];       // 1200000
  const int nB = (N + 63) / 64;    // 1563

  // Workspace: featb 12.8MB | featq 6.4MB | Wb 16KB | recs 6.4MB | gCursor
  unsigned short* featb = (unsigned short*)d_ws;
  unsigned char*  featq = (unsigned char*)(featb + (size_t)N * 64);
  unsigned short* Wb    = (unsigned short*)(featq + (size_t)N * 64);
  unsigned* recs   = (unsigned*)(Wb + 64 * 128);
  int*      gCursor = (int*)(recs + (size_t)NB_MAX * CAP);

  hipMemsetAsync(gCursor, 0, NB_MAX * sizeof(int), stream);

  int nChunks = N * 8;  // 8-float conversion chunks
  int gB = (E + BT_EDGES - 1) / BT_EDGES;  // 235 blocks (one per CU)

  k_build<<<gB, BT_TPB, 0, stream>>>(feat, src, dst, ew, em, Ws, Wn,
                                     gCursor, recs, featb, featq, Wb,
                                     E, nChunks, nB);
  sage_gather_gemm<<<nB, 256, 0, stream>>>(featb, featq, Wb, gCursor, recs,
                                           bs, bn, out, N);
}

// Round 8
// 156.532 us; speedup vs baseline: 1.0396x; 1.0022x over previous
//
#include <hip/hip_runtime.h>

#define NB_MAX   1568   // buckets: ceil(100000/64)=1563, padded
#define CAP      1024   // fixed per-bucket record capacity (mean 768, +9σ safe)
#define BT_EDGES 5120   // edges per build tile -> grid 235 <= 256 CUs (no 2-block tail)
#define BT_TPB   1024
#define EPE      5      // edges per thread in build (5120/1024)

typedef __attribute__((ext_vector_type(4))) float floatx4;
typedef __attribute__((ext_vector_type(2))) float floatx2;
typedef __attribute__((ext_vector_type(8))) short bf16x8;
typedef __attribute__((ext_vector_type(4))) unsigned uintx4;

__device__ __forceinline__ unsigned short f32_to_bf16(float f) {
  unsigned u = __float_as_uint(f);
  u = (u + 0x7fffu + ((u >> 16) & 1u)) >> 16;  // RNE
  return (unsigned short)u;
}
__device__ __forceinline__ unsigned pack2(float a, float b) {
  return (unsigned)f32_to_bf16(a) | ((unsigned)f32_to_bf16(b) << 16);
}
__device__ __forceinline__ bf16x8 zero_bf16x8() {
  bf16x8 v;
#pragma unroll
  for (int i = 0; i < 8; ++i) v[i] = 0;
  return v;
}

// ---- fp8 e4m3fn helpers (HW path on gfx950; software fallback) ------------
#if __has_builtin(__builtin_amdgcn_cvt_pk_fp8_f32)
__device__ __forceinline__ unsigned pack_fp8x4(float a, float b, float c, float d) {
  unsigned v = (unsigned)__builtin_amdgcn_cvt_pk_fp8_f32(a, b, 0, false);
  v = (unsigned)__builtin_amdgcn_cvt_pk_fp8_f32(c, d, (int)v, true);
  return v;
}
#else
__device__ __forceinline__ unsigned sw_f32_fp8(float f) {
  unsigned u = __float_as_uint(f);
  unsigned s = (u >> 24) & 0x80u;
  unsigned au = u & 0x7fffffffu;
  if (au > 0x43E00000u) au = 0x43E00000u;      // clamp to 448
  au += 0x7FFFFu + ((au >> 20) & 1u);          // RNE at bit 20
  int e = (int)(au >> 23) - 120;               // fp8 exponent
  if (e <= 0) return s;                        // flush underflow to ±0
  return s | ((unsigned)e << 3) | ((au >> 20) & 7u);
}
__device__ __forceinline__ unsigned pack_fp8x4(float a, float b, float c, float d) {
  return sw_f32_fp8(a) | (sw_f32_fp8(b) << 8) | (sw_f32_fp8(c) << 16) |
         (sw_f32_fp8(d) << 24);
}
#endif

#if __has_builtin(__builtin_amdgcn_cvt_pk_f32_fp8)
__device__ __forceinline__ void dec4(float* acc, unsigned w32, float wt) {
  floatx2 f0 = __builtin_amdgcn_cvt_pk_f32_fp8((int)w32, false);
  floatx2 f1 = __builtin_amdgcn_cvt_pk_f32_fp8((int)w32, true);
  acc[0] += wt * f0.x; acc[1] += wt * f0.y;
  acc[2] += wt * f1.x; acc[3] += wt * f1.y;
}
#else
__device__ __forceinline__ float sw_fp8_f32(unsigned b) {
  unsigned s = (b & 0x80u) << 24;
  unsigned e = (b >> 3) & 0xFu;
  unsigned m = b & 7u;
  float fn = __uint_as_float(s | ((e + 120u) << 23) | (m << 20));
  float fd = (float)(int)m * 0.001953125f;      // 2^-9
  fd = (b & 0x80u) ? -fd : fd;
  return e ? fn : fd;
}
__device__ __forceinline__ void dec4(float* acc, unsigned w32, float wt) {
  acc[0] += wt * sw_fp8_f32(w32 & 0xFF);
  acc[1] += wt * sw_fp8_f32((w32 >> 8) & 0xFF);
  acc[2] += wt * sw_fp8_f32((w32 >> 16) & 0xFF);
  acc[3] += wt * sw_fp8_f32(w32 >> 24);
}
#endif

// ---------------------------------------------------------------------------
// Single-pass build (v7 — session best): fused edge-stream loads in pass 1.
// The rec32 word (src | dL<<17 | wq<<23) is precomputed into registers, so
// the src/ew/em load latency (~600cy, HBM) overlaps the histogram/scan/
// reserve ladder instead of serializing after it; pass 2 is pure LDS.
// featq is a SINGLE row-major plane (64B rows -> minimal 1 transaction/edge
// in gather; r19 dim-split and r20 src-split variants both measured worse).
// Record (32-bit): src(0..16) | dL(17..22) | w9(23..31).
// LDS: stage 20K + stageB 10K + A/B 12.5K = 43.3 KB (1 block/CU).
// ---------------------------------------------------------------------------
__global__ __launch_bounds__(BT_TPB) void k_build(
    const float* __restrict__ feat, const int* __restrict__ src,
    const int* __restrict__ dst, const float* __restrict__ ew,
    const float* __restrict__ em, const float* __restrict__ Ws,
    const float* __restrict__ Wn, int* __restrict__ gCursor,
    unsigned* __restrict__ recs, unsigned short* __restrict__ featb,
    unsigned char* __restrict__ featq, unsigned short* __restrict__ Wb,
    int E, int nChunks, int nB) {
  __shared__ unsigned stage[BT_EDGES];         // bucket-sorted rec32 (20 KB)
  __shared__ unsigned short stageB[BT_EDGES];  // bucket id per slot   (10 KB)
  __shared__ int A[NB_MAX];                    // loff -> writebase-loff
  __shared__ int B[NB_MAX];                    // cnt -> cursor -> ends
  __shared__ int waveSums[16];

  const int t = threadIdx.x;
  const int lane = t & 63;
  const int wvid = t >> 6;
  const int e0 = blockIdx.x * BT_EDGES;
  const int eEnd = min(e0 + BT_EDGES, E);
  const int nLocal = eEnd - e0;

  for (int i = t; i < NB_MAX; i += BT_TPB) B[i] = 0;
  __syncthreads();

  // pass 1: histogram + full record precompute (loads overlap scan below)
  int dreg[EPE];        // dst (or -1)
  unsigned rreg[EPE];   // precomputed rec32
#pragma unroll
  for (int k = 0; k < EPE; ++k) {
    int i = e0 + k * BT_TPB + t;
    dreg[k] = -1;
    if (i < eEnd) {
      int d = __builtin_nontemporal_load(&dst[i]);
      dreg[k] = d;
      atomicAdd(&B[d >> 6], 1);
      float w = __builtin_nontemporal_load(&ew[i]) *
                __builtin_nontemporal_load(&em[i]);
      int wq = (int)(w * 511.0f + 0.5f);
      if (wq > 511) wq = 511;
      rreg[k] = (unsigned)__builtin_nontemporal_load(&src[i]) |
                ((unsigned)(d & 63) << 17) | ((unsigned)wq << 23);
    }
  }
  __syncthreads();

  // exclusive scan of B -> A via wave shuffles (EPT=2, 1024*2=2048 >= NB_MAX)
  {
    const int EPT = 2;
    int b0 = t * EPT;
    int v[EPT];
    int sum = 0;
#pragma unroll
    for (int j = 0; j < EPT; ++j) {
      v[j] = (b0 + j < nB) ? B[b0 + j] : 0;
      sum += v[j];
    }
    int x = sum;
#pragma unroll
    for (int d = 1; d < 64; d <<= 1) {
      int y = __shfl_up(x, d, 64);
      if (lane >= d) x += y;
    }
    if (lane == 63) waveSums[wvid] = x;
    __syncthreads();
    int wprefix = 0;
    for (int i = 0; i < wvid; ++i) wprefix += waveSums[i];
    int run = wprefix + x - sum;
#pragma unroll
    for (int j = 0; j < EPT; ++j) {
      if (b0 + j < nB) A[b0 + j] = run;
      run += v[j];
    }
  }
  __syncthreads();

  // reserve global ranges; B becomes staging cursor, A becomes write delta
  for (int i = t; i < nB; i += BT_TPB) {
    int c = B[i];
    int l = A[i];
    int g = c ? atomicAdd(&gCursor[i], c) : 0;
    A[i] = i * CAP + g - l;
    B[i] = l;
  }
  __syncthreads();

  // pass 2: stage rec32 + bucket id, bucket-sorted (pure LDS now)
#pragma unroll
  for (int k = 0; k < EPE; ++k) {
    if (dreg[k] >= 0) {
      int bkt = dreg[k] >> 6;
      int r = atomicAdd(&B[bkt], 1);
      stage[r] = rreg[k];
      stageB[r] = (unsigned short)bkt;
    }
  }
  __syncthreads();

  // pass 3: coalesced write-out; bucket id read directly (depth-2 LDS chain)
  for (int i = t; i < nLocal; i += BT_TPB) {
    int bkt = stageB[i];
    int pos = A[bkt] + i;
    if (pos < (bkt + 1) * CAP)  // capacity guard (never fires statistically)
      recs[pos] = stage[i];
  }

  // feat -> bf16 AND fp8 (one read, two writes; grid-stride tail work)
  for (int c = blockIdx.x * BT_TPB + t; c < nChunks; c += gridDim.x * BT_TPB) {
    const floatx4* fp = reinterpret_cast<const floatx4*>(feat) + (size_t)c * 2;
    floatx4 a = __builtin_nontemporal_load(fp);
    floatx4 b = __builtin_nontemporal_load(fp + 1);
    uintx4 o;
    o.x = pack2(a.x, a.y);
    o.y = pack2(a.z, a.w);
    o.z = pack2(b.x, b.y);
    o.w = pack2(b.z, b.w);
    __builtin_nontemporal_store(o, reinterpret_cast<uintx4*>(featb) + c);
    uint2 q8;
    q8.x = pack_fp8x4(a.x, a.y, a.z, a.w);
    q8.y = pack_fp8x4(b.x, b.y, b.z, b.w);
    reinterpret_cast<uint2*>(featq)[c] = q8;  // cached: gather re-reads this
  }

  // W -> bf16 j-major block (block 0 only)
  if (blockIdx.x == 0) {
    for (int i = t; i < 1024; i += BT_TPB) {
      int j = i >> 4, c4 = i & 15;
      float4 w4 = reinterpret_cast<const float4*>(Ws)[i];
      float4 n4 = reinterpret_cast<const float4*>(Wn)[i];
      *reinterpret_cast<uint2*>(&Wb[j * 128 + c4 * 4]) =
          make_uint2(pack2(w4.x, w4.y), pack2(w4.z, w4.w));
      *reinterpret_cast<uint2*>(&Wb[j * 128 + 64 + c4 * 4]) =
          make_uint2(pack2(n4.x, n4.y), pack2(n4.z, n4.w));
    }
  }
}

// ---------------------------------------------------------------------------
// Fused gather + dual-linear (r18 — session best, 154.6 us total): 256
// threads, 4 lanes/node, all 1563 blocks co-resident (the round-4 win), one
// walk per edge (minimal 1x64B-line transaction per edge), self-term featb
// rows + biases issued between the An-write and the final barrier so their
// ~600cy cold-HBM latency hides under barrier-straggler slack.
// Measured-null alternatives (kept out): deeper prefetch (r15), nt-only
// (r16 delta), degree permutation (r14), dim-plane split (r19, 2x
// transactions), src-half two-phase (r20, overhead > residency gain).
// LDS 18.2 KB; __launch_bounds__(256,8) -> 8 blocks/CU, 32 waves/CU.
// ---------------------------------------------------------------------------
__global__ __launch_bounds__(256, 8) void sage_gather_gemm(
    const unsigned short* __restrict__ featb,
    const unsigned char* __restrict__ featq,
    const unsigned short* __restrict__ Wb, const int* __restrict__ gCursor,
    const unsigned* __restrict__ recs, const float* __restrict__ bs,
    const float* __restrict__ bn, float* __restrict__ out, int N) {
  __shared__ unsigned short An[64][72];  // h_neigh bf16; stride 72
  __shared__ unsigned rawL[CAP];         // 4 KB
  __shared__ unsigned srtL[CAP];         // 4 KB
  __shared__ int cntS[64], offS[64], curS[64];

  const int t = threadIdx.x;
  const int b = blockIdx.x;
  const int n0 = b * 64;
  const int base = b * CAP;
  const int cb = min(gCursor[b], CAP);

  if (t < 64) cntS[t] = 0;
  __syncthreads();

  // merged: coalesced record load + LDS stash + histogram in one sweep
  for (int i = t; i < cb; i += 256) {
    unsigned r = __builtin_nontemporal_load(&recs[base + i]);
    rawL[i] = r;
    atomicAdd(&cntS[(r >> 17) & 63], 1);
  }
  __syncthreads();

  // exclusive scan of 64 counters: wave-0 shuffle scan
  if (t < 64) {
    int c = cntS[t];
    int x = c;
#pragma unroll
    for (int d = 1; d < 64; d <<= 1) {
      int y = __shfl_up(x, d, 64);
      if (t >= d) x += y;
    }
    offS[t] = x - c;
    curS[t] = x - c;
  }
  __syncthreads();

  // permute into node-sorted order (LDS -> LDS)
  for (int i = t; i < cb; i += 256) {
    unsigned r = rawL[i];
    int p = atomicAdd(&curS[(r >> 17) & 63], 1);
    srtL[p] = r;
  }
  __syncthreads();

  // MFMA-phase lane mapping (also used for the hoisted prefetch below)
  const int wv = t >> 6;        // node tile (16 nodes)
  const int ln = t & 63;
  const int col = ln & 15;
  const int quad = ln >> 4;
  const int gn = n0 + wv * 16 + col;
  bf16x8 af0 = zero_bf16x8(), af1 = zero_bf16x8();

  // per-node gather: 4 lanes/node (dim-quads); each lane walks all deg edges
  {
    const int nl = t >> 2;        // local node 0..63
    const int q  = t & 3;         // 16-dim chunk
    const int deg = cntS[nl], off = offS[nl];
    float acc[16];
#pragma unroll
    for (int i = 0; i < 16; ++i) acc[i] = 0.f;
    const uint4* fq = reinterpret_cast<const uint4*>(featq);  // row = 4 uint4

    // 2-deep single-edge pipeline; u regs zero-init so a w=0 decode can
    // never be 0*NaN (encoder clamps to 448, no e4m3fn NaN stored).
    uint4 uC = {0, 0, 0, 0}, uN = {0, 0, 0, 0};
    float wC = 0.f, wN = 0.f;
    if (deg > 0) {
      unsigned r0 = srtL[off];
      uC = fq[(size_t)(r0 & 0x1FFFF) * 4 + q];
      wC = (float)(r0 >> 23) * (1.0f / 511.0f);
    }
    if (deg > 1) {
      unsigned r1 = srtL[off + 1];
      uN = fq[(size_t)(r1 & 0x1FFFF) * 4 + q];
      wN = (float)(r1 >> 23) * (1.0f / 511.0f);
    }
    for (int m = 0; m < deg; ++m) {
      uint4 u = uC;
      float w = wC;
      uC = uN; wC = wN;
      if (m + 2 < deg) {
        unsigned rn = srtL[off + m + 2];
        uN = fq[(size_t)(rn & 0x1FFFF) * 4 + q];
        wN = (float)(rn >> 23) * (1.0f / 511.0f);
      }
      dec4(acc + 0, u.x, w);
      dec4(acc + 4, u.y, w);
      dec4(acc + 8, u.z, w);
      dec4(acc + 12, u.w, w);
    }

    float inv = 1.0f / fmaxf((float)deg, 1.0f);
#pragma unroll
    for (int i = 0; i < 16; ++i) acc[i] *= inv;
    uint4 o0, o1;
    o0.x = pack2(acc[0], acc[1]);
    o0.y = pack2(acc[2], acc[3]);
    o0.z = pack2(acc[4], acc[5]);
    o0.w = pack2(acc[6], acc[7]);
    o1.x = pack2(acc[8], acc[9]);
    o1.y = pack2(acc[10], acc[11]);
    o1.z = pack2(acc[12], acc[13]);
    o1.w = pack2(acc[14], acc[15]);
    *reinterpret_cast<uint4*>(&An[nl][q * 16]) = o0;
    *reinterpret_cast<uint4*>(&An[nl][q * 16 + 8]) = o1;
  }

  // hoisted: issue self-term rows + biases NOW; latency hides under the
  // barrier wait for straggler waves still in their gather loops.
  if (gn < N) {
    af0 = __builtin_nontemporal_load(
        reinterpret_cast<const bf16x8*>(featb + (size_t)gn * 64 + quad * 8));
    af1 = __builtin_nontemporal_load(
        reinterpret_cast<const bf16x8*>(featb + (size_t)gn * 64 + 32 + quad * 8));
  }
  floatx4 acc4[4];
#pragma unroll
  for (int jt = 0; jt < 4; ++jt) {
    float bb = bs[jt * 16 + col] + bn[jt * 16 + col];
    acc4[jt] = (floatx4){bb, bb, bb, bb};
  }
  __syncthreads();

  // MFMA phase: 4 waves = 4 node-tiles; each wave does all 4 j-tiles
#pragma unroll
  for (int kk = 0; kk < 4; ++kk) {
    bf16x8 af;
    if (kk == 0)      af = af0;
    else if (kk == 1) af = af1;
    else
      af = *reinterpret_cast<const bf16x8*>(
          &An[wv * 16 + col][(kk - 2) * 32 + quad * 8]);
#pragma unroll
    for (int jt = 0; jt < 4; ++jt) {
      bf16x8 bf = *reinterpret_cast<const bf16x8*>(
          Wb + (jt * 16 + col) * 128 + kk * 32 + quad * 8);
      acc4[jt] = __builtin_amdgcn_mfma_f32_16x16x32_bf16(af, bf, acc4[jt], 0, 0, 0);
    }
  }

#pragma unroll
  for (int jt = 0; jt < 4; ++jt) {
#pragma unroll
    for (int r = 0; r < 4; ++r) {
      int m = quad * 4 + r;
      int g2 = n0 + wv * 16 + m;
      if (g2 < N)
        __builtin_nontemporal_store(acc4[jt][r],
                                    &out[(size_t)g2 * 64 + jt * 16 + col]);
    }
  }
}

extern "C" void kernel_launch(void* const* d_in, const int* in_sizes, int n_in,
                              void* d_out, int out_size, void* d_ws, size_t ws_size,
                              hipStream_t stream) {
  const float* feat = (const float*)d_in[0];
  const int*   src  = (const int*)d_in[1];
  const int*   dst  = (const int*)d_in[2];
  const float* ew   = (const float*)d_in[3];
  const float* em   = (const float*)d_in[4];
  const float* Ws   = (const float*)d_in[5];
  const float* bs   = (const float*)d_in[6];
  const float* Wn   = (const float*)d_in[7];
  const float* bn   = (const float*)d_in[8];
  float* out = (float*)d_out;

  const int N = in_sizes[0] / 64;  // 100000
  const int E = in_sizes[1];       // 1200000
  const int nB = (N + 63) / 64;    // 1563

  // Workspace: featb 12.8MB | featq 6.4MB | Wb 16KB | recs 6.4MB | gCursor
  unsigned short* featb = (unsigned short*)d_ws;
  unsigned char*  featq = (unsigned char*)(featb + (size_t)N * 64);
  unsigned short* Wb    = (unsigned short*)(featq + (size_t)N * 64);
  unsigned* recs   = (unsigned*)(Wb + 64 * 128);
  int*      gCursor = (int*)(recs + (size_t)NB_MAX * CAP);

  hipMemsetAsync(gCursor, 0, NB_MAX * sizeof(int), stream);

  int nChunks = N * 8;  // 8-float conversion chunks
  int gB = (E + BT_EDGES - 1) / BT_EDGES;  // 235 blocks (one per CU)

  k_build<<<gB, BT_TPB, 0, stream>>>(feat, src, dst, ew, em, Ws, Wn,
                                     gCursor, recs, featb, featq, Wb,
                                     E, nChunks, nB);
  sage_gather_gemm<<<nB, 256, 0, stream>>>(featb, featq, Wb, gCursor, recs,
                                           bs, bn, out, N);
}